// Round 3
// baseline (499.466 us; speedup 1.0000x reference)
//
#include <hip/hip_runtime.h>

typedef __attribute__((ext_vector_type(4))) float   f32x4;
typedef __attribute__((ext_vector_type(8))) __bf16  bf16x8;
typedef unsigned short u16;
typedef __attribute__((ext_vector_type(8))) unsigned short u16x8;
typedef __attribute__((ext_vector_type(4))) unsigned short u16x4;

__device__ __forceinline__ u16 f2bf(float f) {
  unsigned u = __builtin_bit_cast(unsigned, f);
  u += 0x7fffu + ((u >> 16) & 1u);
  return (u16)(u >> 16);
}
__device__ __forceinline__ float bf2f(u16 h) {
  unsigned u = ((unsigned)h) << 16;
  return __builtin_bit_cast(float, u);
}

__device__ __forceinline__ void gld16(const void* g, void* l) {
  __builtin_amdgcn_global_load_lds(
      (const __attribute__((address_space(1))) void*)g,
      (__attribute__((address_space(3))) void*)l, 16, 0, 0);
}

// C[m,n] = sum_k A[m,k] * B[n,k]   (B stored K-major, i.e. B^T input)
// 128x128 tile, BK=32, 4 waves (2x2 of 64x64), 16x16x32 bf16 MFMA.
// 3-buffer cyclic LDS, 2-tiles-ahead prefetch, COUNTED vmcnt (T4): loads
// stay in flight across barriers; vmcnt never drains to 0 mid-loop.
// Staging: global_load_lds w16, linear LDS dest, inverse-swizzled global
// source + swizzled ds_read (T2, rule 21).
// AF32: A is f32 in HBM, staged raw, converted to bf16 at fragment read.
// EPI: 0 = bf16 store, 1 = K normal + V transposed (via LDS transpose,
//      256B-coalesced), 2 = scores(scale+mask), 3 = relu f32
// SWZ: bijective XCD-contiguous tile remap (T1).
template<int AF32, int EPI, int SWZ>
__global__ __launch_bounds__(256)
void gemm_k(const void* __restrict__ Ap, const u16* __restrict__ Bp,
            void* __restrict__ Cp, void* __restrict__ Cp2,
            const int* __restrict__ maskp,
            int K, long sA, long sB, long sC, long sM, int ldc, float scale)
{
  __shared__ float Asf[3][AF32 ? 4096 : 4];   // f32 A tile 128x32
  __shared__ u16   Asb[3][AF32 ? 4 : 4096];   // bf16 A tile 128x32
  __shared__ u16   Bs [3][4096];              // bf16 B tile 128x32

  int bx = blockIdx.x, by = blockIdx.y;
  if constexpr (SWZ) {
    int nwg = gridDim.x * gridDim.y;          // divisible by 8
    int h = bx + gridDim.x * by;
    int q = nwg >> 3;
    int s = (h & 7) * q + (h >> 3);           // XCD h%8 gets contiguous tiles
    bx = s % gridDim.x; by = s / gridDim.x;
  }
  const int t = threadIdx.x, z = blockIdx.z;
  const int n0 = bx * 128, m0 = by * 128;
  const int KT = K / 32;
  const u16* Bb = Bp + (long)z * sB;

  const int w = t >> 6, lane = t & 63;
  const int m0w = (w >> 1) * 64, n0w = (w & 1) * 64;
  const int lr = lane & 15, lc = lane >> 4;

  f32x4 acc[4][4];
#pragma unroll
  for (int i = 0; i < 4; i++)
#pragma unroll
    for (int j = 0; j < 4; j++) acc[i][j] = f32x4{0.f, 0.f, 0.f, 0.f};

  auto stage = [&](int buf, int kt) {
    if constexpr (AF32) {
      const float* A = (const float*)Ap + (long)z * sA;
#pragma unroll
      for (int i = 0; i < 4; i++) {
        int chunk = w * 4 + i;                 // 16 chunks of 1KB
        int row = chunk * 8 + (lane >> 3);     // 8 rows (128B) per chunk
        int cc  = lane & 7;                    // 16B slot within row
        const float* g = A + (long)(m0 + row) * K + kt * 32 + ((cc ^ (row & 7)) << 2);
        gld16(g, (void*)&Asf[buf][chunk * 256]);
      }
    } else {
      const u16* A = (const u16*)Ap + (long)z * sA;
#pragma unroll
      for (int i = 0; i < 2; i++) {
        int chunk = w * 2 + i;                 // 8 chunks of 1KB
        int row = chunk * 16 + (lane >> 2);    // 16 rows (64B) per chunk
        int cc  = lane & 3;
        const u16* g = A + (long)(m0 + row) * K + kt * 32 + ((cc ^ ((row >> 1) & 3)) << 3);
        gld16(g, (void*)&Asb[buf][chunk * 512]);
      }
    }
#pragma unroll
    for (int i = 0; i < 2; i++) {
      int chunk = w * 2 + i;
      int row = chunk * 16 + (lane >> 2);
      int cc  = lane & 3;
      const u16* g = Bb + (long)(n0 + row) * K + kt * 32 + ((cc ^ ((row >> 1) & 3)) << 3);
      gld16(g, (void*)&Bs[buf][chunk * 512]);
    }
  };

  auto compute = [&](int buf) {
    bf16x8 af[4], bv[4];
#pragma unroll
    for (int f = 0; f < 4; f++) {
      const int R = m0w + f * 16 + lr;
      if constexpr (AF32) {
        f32x4 lo = *(const f32x4*)&Asf[buf][R * 32 + (((lc * 2 + 0) ^ (R & 7)) << 2)];
        f32x4 hi = *(const f32x4*)&Asf[buf][R * 32 + (((lc * 2 + 1) ^ (R & 7)) << 2)];
        bf16x8 v;
#pragma unroll
        for (int j = 0; j < 4; j++) { v[j] = (__bf16)lo[j]; v[4 + j] = (__bf16)hi[j]; }
        af[f] = v;
      } else {
        af[f] = __builtin_bit_cast(bf16x8,
            *(const u16x8*)&Asb[buf][R * 32 + ((lc ^ ((R >> 1) & 3)) << 3)]);
      }
      const int R2 = n0w + f * 16 + lr;
      bv[f] = __builtin_bit_cast(bf16x8,
          *(const u16x8*)&Bs[buf][R2 * 32 + ((lc ^ ((R2 >> 1) & 3)) << 3)]);
    }
#pragma unroll
    for (int i = 0; i < 4; i++)
#pragma unroll
      for (int j = 0; j < 4; j++)
        acc[i][j] = __builtin_amdgcn_mfma_f32_16x16x32_bf16(af[i], bv[j], acc[i][j], 0, 0, 0);
  };

  // counted-vmcnt waits: OUT = gld16 per wave per stage (6 f32-A, 4 bf16-A)
#define WAIT_OUT() do { if constexpr (AF32) asm volatile("s_waitcnt vmcnt(6)" ::: "memory"); \
                        else               asm volatile("s_waitcnt vmcnt(4)" ::: "memory"); } while (0)
#define WAIT_0()   asm volatile("s_waitcnt vmcnt(0)" ::: "memory")
#define BAR()      do { __builtin_amdgcn_s_barrier(); __builtin_amdgcn_sched_barrier(0); } while (0)

  stage(0, 0);
  stage(1, 1);
  WAIT_OUT();            // tile 0 landed (tile 1 still in flight)
  BAR();
  for (int kt = 0; kt < KT; ++kt) {
    if (kt + 2 < KT) stage((kt + 2) % 3, kt + 2);
    compute(kt % 3);
    if (kt + 1 < KT) {
      if (kt + 2 < KT) WAIT_OUT(); else WAIT_0();
      BAR();
    }
  }
#undef WAIT_OUT
#undef WAIT_0
#undef BAR

  // -------- epilogue --------
  if constexpr (EPI == 1) {
    if (n0 >= 512) {
      // V block: transpose 128(kv) x 128(d) through LDS, store Vt rows
      // in 256B-contiguous segments.
      u16* T = (u16*)&Asf[0][0];               // 34.8KB needed, 48KB avail
      __syncthreads();                          // all waves done with LDS bufs
#pragma unroll
      for (int i = 0; i < 4; i++)
#pragma unroll
        for (int j = 0; j < 4; j++) {
          const int lkv = m0w + i * 16 + lc * 4;
          const int ld  = n0w + j * 16 + lr;
          u16x4 h;
#pragma unroll
          for (int ii = 0; ii < 4; ii++) h[ii] = f2bf(acc[i][j][ii]);
          *(u16x4*)&T[ld * 136 + lkv] = h;
        }
      __syncthreads();
      u16* C2 = (u16*)Cp2;
      const int b = m0 >> 11;                   // local batch index
      const int kvb = m0 & 2047;
#pragma unroll
      for (int p = 0; p < 8; ++p) {
        const int ld = p * 16 + (t >> 4);
        const int kq = (t & 15) * 8;
        u16x8 v = *(const u16x8*)&T[ld * 136 + kq];
        const long d = (n0 - 512) + ld;
        *(u16x8*)(C2 + ((long)b * 512 + d) * 2048 + kvb + kq) = v;
      }
      return;
    }
    // K block: direct stores
    u16* C = (u16*)Cp;
#pragma unroll
    for (int i = 0; i < 4; i++)
#pragma unroll
      for (int j = 0; j < 4; j++) {
        const int mb = m0 + m0w + i * 16 + lc * 4;
        const int n  = n0 + n0w + j * 16 + lr;
#pragma unroll
        for (int ii = 0; ii < 4; ii++)
          C[(long)(mb + ii) * 512 + n] = f2bf(acc[i][j][ii]);
      }
    return;
  }

#pragma unroll
  for (int i = 0; i < 4; i++) {
#pragma unroll
    for (int j = 0; j < 4; j++) {
      const int mb = m0 + m0w + i * 16 + lc * 4;
      const int n  = n0 + n0w + j * 16 + lr;
      if constexpr (EPI == 0) {
        u16* C = (u16*)Cp + (long)z * sC;
#pragma unroll
        for (int ii = 0; ii < 4; ii++)
          C[(long)(mb + ii) * ldc + n] = f2bf(acc[i][j][ii]);
      } else if constexpr (EPI == 2) {
        const int* mk = maskp + (long)z * sM;
        u16* C = (u16*)Cp + (long)z * sC;
        const float bias = mk[n] ? 0.f : -1e10f;
#pragma unroll
        for (int ii = 0; ii < 4; ii++)
          C[(long)(mb + ii) * ldc + n] = f2bf(acc[i][j][ii] * scale + bias);
      } else if constexpr (EPI == 3) {
        float* C = (float*)Cp + (long)z * sC;
#pragma unroll
        for (int ii = 0; ii < 4; ii++)
          C[(long)(mb + ii) * ldc + n] = fmaxf(acc[i][j][ii], 0.f);
      }
    }
  }
}

// convert + concat [Wq;Wk;Wv] f32 [3*512,512] -> bf16
__global__ __launch_bounds__(256)
void wconv_k(const float* __restrict__ Wq, const float* __restrict__ Wk,
             const float* __restrict__ Wv, u16* __restrict__ Wb)
{
  long i4 = (long)blockIdx.x * 256 + threadIdx.x;
  long e  = i4 * 4;
  const float* W = (e < 262144) ? Wq : (e < 524288 ? Wk : Wv);
  long off = e & 262143;
  f32x4 f = *(const f32x4*)(W + off);
  u16x4 h;
#pragma unroll
  for (int j = 0; j < 4; j++) h[j] = f2bf(f[j]);
  *(u16x4*)(Wb + e) = h;
}

// f32 -> bf16, 8 elems/thread (exact multiple)
__global__ __launch_bounds__(256)
void cvt_k(const float* __restrict__ in, u16* __restrict__ out)
{
  long i = ((long)blockIdx.x * 256 + threadIdx.x) * 8;
  f32x4 a = *(const f32x4*)(in + i);
  f32x4 b = *(const f32x4*)(in + i + 4);
  u16x8 h;
#pragma unroll
  for (int j = 0; j < 4; j++) { h[j] = f2bf(a[j]); h[4 + j] = f2bf(b[j]); }
  *(u16x8*)(out + i) = h;
}

// in-place row softmax over 2048 bf16 logits
__global__ __launch_bounds__(256)
void softmax_k(u16* __restrict__ S)
{
  const long row = blockIdx.x;
  const int  t   = threadIdx.x;
  u16* R = S + row * 2048;
  u16x8 v = *(const u16x8*)(R + t * 8);
  float f[8];
#pragma unroll
  for (int j = 0; j < 8; j++) f[j] = bf2f(v[j]);
  float m = f[0];
#pragma unroll
  for (int j = 1; j < 8; j++) m = fmaxf(m, f[j]);
#pragma unroll
  for (int off = 32; off > 0; off >>= 1) m = fmaxf(m, __shfl_xor(m, off));
  __shared__ float red[4], red2[4];
  const int w = t >> 6;
  if ((t & 63) == 0) red[w] = m;
  __syncthreads();
  m = fmaxf(fmaxf(red[0], red[1]), fmaxf(red[2], red[3]));
  float e[8], s = 0.f;
#pragma unroll
  for (int j = 0; j < 8; j++) { e[j] = __expf(f[j] - m); s += e[j]; }
#pragma unroll
  for (int off = 32; off > 0; off >>= 1) s += __shfl_xor(s, off);
  if ((t & 63) == 0) red2[w] = s;
  __syncthreads();
  s = red2[0] + red2[1] + red2[2] + red2[3];
  const float inv = 1.f / s;
  u16x8 o;
#pragma unroll
  for (int j = 0; j < 8; j++) o[j] = f2bf(e[j] * inv);
  *(u16x8*)(R + t * 8) = o;
}

extern "C" void kernel_launch(void* const* d_in, const int* in_sizes, int n_in,
                              void* d_out, int out_size, void* d_ws, size_t ws_size,
                              hipStream_t stream)
{
  const float* mf   = (const float*)d_in[0];   // [64,128,512]
  const float* x    = (const float*)d_in[1];   // [64,2048,512]
  const int*   mask = (const int*)d_in[2];     // [64,2048]
  const float* Wq   = (const float*)d_in[3];
  const float* Wk   = (const float*)d_in[4];
  const float* Wv   = (const float*)d_in[5];
  float* out = (float*)d_out;

  u16* ws  = (u16*)d_ws;
  u16* Wb  = ws;                     // 1536*512 = 786432 u16
  u16* mfb = Wb + 786432;            // 8192*512 = 4194304 u16
  u16* Qb  = mfb + 4194304;          // 8192*512 = 4194304 u16
  u16* dyn = Qb + 4194304;

  // per-batch scratch: K(2MB) + Vt(2MB) + S(0.5MB) = 4718592 B
  const size_t fixedB = (size_t)(786432 + 4194304 + 4194304) * 2;
  int CB = 64;
  while (CB > 1 && fixedB + (size_t)CB * 4718592ull > ws_size) CB >>= 1;

  u16* Kc  = dyn;                               // [CB*2048, 512]
  u16* Vtc = Kc + (size_t)CB * 1048576;         // [CB, 512, 2048]
  u16* Sc  = Vtc + (size_t)CB * 1048576;        // [CB, 128, 2048]

  const float scale = 0.044194173824159216f;    // 1/sqrt(512)

  wconv_k<<<768, 256, 0, stream>>>(Wq, Wk, Wv, Wb);
  cvt_k<<<2048, 256, 0, stream>>>(mf, mfb);     // 4194304 elems

  // Q projection: M=8192, N=512, K=512, bf16 A
  gemm_k<0, 0, 0><<<dim3(4, 64, 1), 256, 0, stream>>>(
      mfb, Wb, Qb, nullptr, nullptr, 512, 0, 0, 0, 0, 512, 1.f);

  for (int bc = 0; bc < 64; bc += CB) {
    const float* xc = x + (long)bc * 2048 * 512;
    // fused K+V projection: f32 A direct, N=1024 (0-511 -> K, 512-1023 -> V^T)
    gemm_k<1, 1, 1><<<dim3(8, CB * 16, 1), 256, 0, stream>>>(
        xc, Wb + 262144, Kc, Vtc, nullptr, 512, 0, 0, 0, 0, 512, 1.f);
    // scores: S[q,kv] = (Q K^T)*scale - (1-mask)*1e10  (bf16)
    gemm_k<0, 2, 0><<<dim3(16, 1, CB), 256, 0, stream>>>(
        Qb + (long)bc * 65536, Kc, Sc, nullptr, mask + (long)bc * 2048,
        512, 65536, 1048576, 262144, 2048, 2048, scale);
    softmax_k<<<CB * 128, 256, 0, stream>>>(Sc);
    // PV: out = relu(P V^T), K=2048, f32 out
    gemm_k<0, 3, 0><<<dim3(4, 1, CB), 256, 0, stream>>>(
        Sc, Vtc, out + (long)bc * 65536, nullptr, nullptr,
        2048, 262144, 1048576, 65536, 0, 512, 1.f);
  }
}

// Round 4
// 403.168 us; speedup vs baseline: 1.2389x; 1.2389x over previous
//
#include <hip/hip_runtime.h>

typedef __attribute__((ext_vector_type(4))) float   f32x4;
typedef __attribute__((ext_vector_type(8))) __bf16  bf16x8;
typedef unsigned short u16;
typedef __attribute__((ext_vector_type(8))) unsigned short u16x8;
typedef __attribute__((ext_vector_type(4))) unsigned short u16x4;

__device__ __forceinline__ u16 f2bf(float f) {
  unsigned u = __builtin_bit_cast(unsigned, f);
  u += 0x7fffu + ((u >> 16) & 1u);
  return (u16)(u >> 16);
}
__device__ __forceinline__ float bf2f(u16 h) {
  unsigned u = ((unsigned)h) << 16;
  return __builtin_bit_cast(float, u);
}
__device__ __forceinline__ void gld16(const void* g, void* l) {
  __builtin_amdgcn_global_load_lds(
      (const __attribute__((address_space(1))) void*)g,
      (__attribute__((address_space(3))) void*)l, 16, 0, 0);
}

// ============================================================================
// 8-phase 256x256 KV-projection kernel (T1+T2+T3+T4+T5 together).
// C[m,n] = sum_k xb[m,k]*Wkv[n,k]; M=CB*2048, N=1024, K=512 (KT=8 K-tiles of 64).
// 512 thr = 8 waves (2M x 4N), per-wave 128x64 out (acc[8][4]).
// LDS 128KB: A[2 slots][2 halves][128][64] + B same. slot = tile&1.
// Schedule per iteration I (tiles a=2I ph1-4, b=2I+1 ph5-8), stages:
//   ph1:A0(b) ph2:A1(b) ph3:B0(a+2) ph4:B1(a+2)+vm4
//   ph5:A0(a+2) ph6:A1(a+2) ph7:B0(b+2) ph8:B1(b+2)+vm4
// Invariants (verified): a region staged in phase p had its last ds_read
// complete before phase p-1's closing barrier; vmcnt(4) at ph4/ph8 leaves
// only the newest 2 half-tiles in flight => every operand landed >=1
// vmcnt+barrier before first read. Guards block-uniform (no barrier skew).
// Swizzle: 16B-slot ^= (row&7) on global source, same XOR on ds_read.
// ============================================================================

#define SYNC_MID do { __builtin_amdgcn_sched_barrier(0); __builtin_amdgcn_s_barrier(); \
  asm volatile("s_waitcnt lgkmcnt(0)" ::: "memory"); __builtin_amdgcn_sched_barrier(0); } while(0)
#define SYNC_END do { __builtin_amdgcn_sched_barrier(0); __builtin_amdgcn_s_barrier(); \
  __builtin_amdgcn_sched_barrier(0); } while(0)
#define VM4 asm volatile("s_waitcnt vmcnt(4)" ::: "memory")
#define VM0 asm volatile("s_waitcnt vmcnt(0)" ::: "memory")

#define LDA(AQ, S, I0) \
  _Pragma("unroll") for (int f = 0; f < 2; ++f) \
  _Pragma("unroll") for (int s = 0; s < 2; ++s) { \
    const int rl = ((I0)+f)*16 + lr; \
    AQ[f*2+s] = *(const u16x8*)&SM[((S)*2 + wr)*8192 + rl*64 + (((s*4+lc) ^ (rl&7))*8)]; }

#define LDB(S) \
  _Pragma("unroll") for (int j = 0; j < 4; ++j) \
  _Pragma("unroll") for (int s = 0; s < 2; ++s) { \
    const int rl = (wc&1)*64 + j*16 + lr; \
    bq[j][s] = *(const u16x8*)&SM[32768 + ((S)*2 + (wc>>1))*8192 + rl*64 + (((s*4+lc) ^ (rl&7))*8)]; }

#define MM(AQ, I0) do { __builtin_amdgcn_s_setprio(1); \
  _Pragma("unroll") for (int f = 0; f < 2; ++f) \
  _Pragma("unroll") for (int j = 0; j < 4; ++j) \
  _Pragma("unroll") for (int s = 0; s < 2; ++s) \
    acc[(I0)+f][j] = __builtin_amdgcn_mfma_f32_16x16x32_bf16( \
      __builtin_bit_cast(bf16x8, AQ[f*2+s]), __builtin_bit_cast(bf16x8, bq[j][s]), \
      acc[(I0)+f][j], 0, 0, 0); \
  __builtin_amdgcn_s_setprio(0); } while(0)

__global__ __launch_bounds__(512, 1)
void kv8_k(const u16* __restrict__ xb, const u16* __restrict__ Wkv,
           u16* __restrict__ Kc, u16* __restrict__ Vt)
{
  __shared__ u16 SM[65536];   // 128 KB
  const int t = threadIdx.x;
  const int w = t >> 6, lane = t & 63;
  const int wr = w >> 2, wc = w & 3;
  const int lr = lane & 15, lc = lane >> 4;

  int bx = blockIdx.x, by = blockIdx.y;
  { // T1 bijective XCD swizzle (nwg divisible by 8)
    int nwg = gridDim.x * gridDim.y;
    int h = bx + 4 * by;
    int q = nwg >> 3;
    int s = (h & 7) * q + (h >> 3);
    bx = s & 3; by = s >> 2;
  }
  const int n0 = bx * 256;
  const int m0 = by * 256;
  const int KT = 8;   // 512/64

  f32x4 acc[8][4];
#pragma unroll
  for (int i = 0; i < 8; i++)
#pragma unroll
    for (int j = 0; j < 4; j++) acc[i][j] = f32x4{0.f, 0.f, 0.f, 0.f};
  u16x8 bq[4][2];

  auto stageA = [&](int T, int h) {          // one 128x64 half-tile, 2 gld16/thread
    const int S = T & 1;
#pragma unroll
    for (int r = 0; r < 2; ++r) {
      const int idx = r * 512 + w * 64;      // wave-uniform 16B-slot base
      const int row = (idx >> 3) + (lane >> 3);
      const int slot = lane & 7;
      const u16* g = xb + (long)(m0 + h * 128 + row) * 512 + T * 64 + ((slot ^ (row & 7)) * 8);
      gld16(g, (void*)&SM[(S * 2 + h) * 8192 + idx * 8]);
    }
  };
  auto stageB = [&](int T, int h) {
    const int S = T & 1;
#pragma unroll
    for (int r = 0; r < 2; ++r) {
      const int idx = r * 512 + w * 64;
      const int row = (idx >> 3) + (lane >> 3);
      const int slot = lane & 7;
      const u16* g = Wkv + (long)(n0 + h * 128 + row) * 512 + T * 64 + ((slot ^ (row & 7)) * 8);
      gld16(g, (void*)&SM[32768 + (S * 2 + h) * 8192 + idx * 8]);
    }
  };

  // prologue: A(0), B(0), B(1); wait A(0),B(0) landed (B(1) stays in flight)
  stageA(0, 0); stageA(0, 1);
  stageB(0, 0); stageB(0, 1);
  stageB(1, 0); stageB(1, 1);
  VM4; __builtin_amdgcn_sched_barrier(0);
  __builtin_amdgcn_s_barrier(); __builtin_amdgcn_sched_barrier(0);

  for (int I = 0; I < KT / 2; ++I) {
    const int a = 2 * I, b = 2 * I + 1;
    const bool g2 = (a + 2) < KT;
    const bool g3 = (b + 2) < KT;
    // ---- tile a (slot 0) ----
    { u16x8 aq[4]; LDB(0); LDA(aq, 0, 0); stageA(b, 0);
      SYNC_MID; MM(aq, 0); SYNC_END; }
    { u16x8 aq[4]; LDA(aq, 0, 2); stageA(b, 1);
      SYNC_MID; MM(aq, 2); SYNC_END; }
    { u16x8 aq[4]; LDA(aq, 0, 4); if (g2) stageB(a + 2, 0);
      SYNC_MID; MM(aq, 4); SYNC_END; }
    { u16x8 aq[4]; LDA(aq, 0, 6); if (g2) stageB(a + 2, 1);
      SYNC_MID; MM(aq, 6); if (g2) { VM4; } else { VM0; } SYNC_END; }
    // ---- tile b (slot 1) ----
    { u16x8 aq[4]; LDB(1); LDA(aq, 1, 0); if (g2) stageA(a + 2, 0);
      SYNC_MID; MM(aq, 0); SYNC_END; }
    { u16x8 aq[4]; LDA(aq, 1, 2); if (g2) stageA(a + 2, 1);
      SYNC_MID; MM(aq, 2); SYNC_END; }
    { u16x8 aq[4]; LDA(aq, 1, 4); if (g3) stageB(b + 2, 0);
      SYNC_MID; MM(aq, 4); SYNC_END; }
    { u16x8 aq[4]; LDA(aq, 1, 6); if (g3) stageB(b + 2, 1);
      SYNC_MID; MM(aq, 6); if (g3) { VM4; } else { VM0; } SYNC_END; }
  }

  // epilogue: cols 0-511 -> Kc [m,512]; cols 512-1023 -> Vt [b][512][2048] (d-major)
#pragma unroll
  for (int i = 0; i < 8; i++) {
#pragma unroll
    for (int j = 0; j < 4; j++) {
      const int ml = wr * 128 + i * 16 + lc * 4;      // local m (0..255)
      const int m  = m0 + ml;
      const int n  = n0 + wc * 64 + j * 16 + lr;
      if (n0 < 512) {
#pragma unroll
        for (int ii = 0; ii < 4; ii++)
          Kc[(long)(m + ii) * 512 + n] = f2bf(acc[i][j][ii]);
      } else {
        const int bb = m >> 11, kv = m & 2047, d = n - 512;
        u16x4 h;
#pragma unroll
        for (int ii = 0; ii < 4; ii++) h[ii] = f2bf(acc[i][j][ii]);
        *(u16x4*)(Vt + ((long)bb * 512 + d) * 2048 + kv) = h;
      }
    }
  }
}

// ============================================================================
// Proven R2 2-buffer GEMM (bf16 A): used for Q-proj, scores, PV.
// EPI: 0 = bf16 store, 2 = scores(scale+mask), 3 = relu f32
// ============================================================================
template<int EPI>
__global__ __launch_bounds__(256)
void gemm_k(const u16* __restrict__ Ap, const u16* __restrict__ Bp,
            void* __restrict__ Cp, const int* __restrict__ maskp,
            int K, long sA, long sB, long sC, long sM, int ldc, float scale)
{
  __shared__ u16 Asb[2][4096];
  __shared__ u16 Bs [2][4096];

  const int t = threadIdx.x, z = blockIdx.z;
  const int n0 = blockIdx.x * 128, m0 = blockIdx.y * 128;
  const int KT = K / 32;
  const u16* Ab = Ap + (long)z * sA;
  const u16* Bb = Bp + (long)z * sB;

  const int w = t >> 6, lane = t & 63;
  const int m0w = (w >> 1) * 64, n0w = (w & 1) * 64;
  const int lr = lane & 15, lc = lane >> 4;

  f32x4 acc[4][4];
#pragma unroll
  for (int i = 0; i < 4; i++)
#pragma unroll
    for (int j = 0; j < 4; j++) acc[i][j] = f32x4{0.f, 0.f, 0.f, 0.f};

  auto stage = [&](int buf, int kt) {
#pragma unroll
    for (int i = 0; i < 2; i++) {
      int chunk = w * 2 + i, row = chunk * 16 + (lane >> 2), cc = lane & 3;
      const u16* g = Ab + (long)(m0 + row) * K + kt * 32 + ((cc ^ ((row >> 1) & 3)) << 3);
      gld16(g, (void*)&Asb[buf][chunk * 512]);
    }
#pragma unroll
    for (int i = 0; i < 2; i++) {
      int chunk = w * 2 + i, row = chunk * 16 + (lane >> 2), cc = lane & 3;
      const u16* g = Bb + (long)(n0 + row) * K + kt * 32 + ((cc ^ ((row >> 1) & 3)) << 3);
      gld16(g, (void*)&Bs[buf][chunk * 512]);
    }
  };
  auto compute = [&](int buf) {
    bf16x8 af[4], bv[4];
#pragma unroll
    for (int f = 0; f < 4; f++) {
      const int R = m0w + f * 16 + lr;
      af[f] = __builtin_bit_cast(bf16x8,
          *(const u16x8*)&Asb[buf][R * 32 + ((lc ^ ((R >> 1) & 3)) << 3)]);
      const int R2 = n0w + f * 16 + lr;
      bv[f] = __builtin_bit_cast(bf16x8,
          *(const u16x8*)&Bs[buf][R2 * 32 + ((lc ^ ((R2 >> 1) & 3)) << 3)]);
    }
#pragma unroll
    for (int i = 0; i < 4; i++)
#pragma unroll
      for (int j = 0; j < 4; j++)
        acc[i][j] = __builtin_amdgcn_mfma_f32_16x16x32_bf16(af[i], bv[j], acc[i][j], 0, 0, 0);
  };

  stage(0, 0);
  __syncthreads();
  int cur = 0;
  for (int kt = 1; kt < KT; ++kt) {
    stage(cur ^ 1, kt);
    compute(cur);
    __syncthreads();
    cur ^= 1;
  }
  compute(cur);

#pragma unroll
  for (int i = 0; i < 4; i++) {
#pragma unroll
    for (int j = 0; j < 4; j++) {
      const int mb = m0 + m0w + i * 16 + lc * 4;
      const int n  = n0 + n0w + j * 16 + lr;
      if constexpr (EPI == 0) {
        u16* C = (u16*)Cp + (long)z * sC;
#pragma unroll
        for (int ii = 0; ii < 4; ii++)
          C[(long)(mb + ii) * ldc + n] = f2bf(acc[i][j][ii]);
      } else if constexpr (EPI == 2) {
        const int* mk = maskp + (long)z * sM;
        u16* C = (u16*)Cp + (long)z * sC;
        const float bias = mk[n] ? 0.f : -1e10f;
#pragma unroll
        for (int ii = 0; ii < 4; ii++)
          C[(long)(mb + ii) * ldc + n] = f2bf(acc[i][j][ii] * scale + bias);
      } else {
        float* C = (float*)Cp + (long)z * sC;
#pragma unroll
        for (int ii = 0; ii < 4; ii++)
          C[(long)(mb + ii) * ldc + n] = fmaxf(acc[i][j][ii], 0.f);
      }
    }
  }
}

// convert + concat [Wq;Wk;Wv] f32 [3*512,512] -> bf16
__global__ __launch_bounds__(256)
void wconv_k(const float* __restrict__ Wq, const float* __restrict__ Wk,
             const float* __restrict__ Wv, u16* __restrict__ Wb)
{
  long i4 = (long)blockIdx.x * 256 + threadIdx.x;
  long e  = i4 * 4;
  const float* W = (e < 262144) ? Wq : (e < 524288 ? Wk : Wv);
  long off = e & 262143;
  f32x4 f = *(const f32x4*)(W + off);
  u16x4 h;
#pragma unroll
  for (int j = 0; j < 4; j++) h[j] = f2bf(f[j]);
  *(u16x4*)(Wb + e) = h;
}

// f32 -> bf16, 8 elems/thread (exact multiple)
__global__ __launch_bounds__(256)
void cvt_k(const float* __restrict__ in, u16* __restrict__ out)
{
  long i = ((long)blockIdx.x * 256 + threadIdx.x) * 8;
  f32x4 a = *(const f32x4*)(in + i);
  f32x4 b = *(const f32x4*)(in + i + 4);
  u16x8 h;
#pragma unroll
  for (int j = 0; j < 4; j++) { h[j] = f2bf(a[j]); h[4 + j] = f2bf(b[j]); }
  *(u16x8*)(out + i) = h;
}

// in-place row softmax over 2048 bf16 logits
__global__ __launch_bounds__(256)
void softmax_k(u16* __restrict__ S)
{
  const long row = blockIdx.x;
  const int  t   = threadIdx.x;
  u16* R = S + row * 2048;
  u16x8 v = *(const u16x8*)(R + t * 8);
  float f[8];
#pragma unroll
  for (int j = 0; j < 8; j++) f[j] = bf2f(v[j]);
  float m = f[0];
#pragma unroll
  for (int j = 1; j < 8; j++) m = fmaxf(m, f[j]);
#pragma unroll
  for (int off = 32; off > 0; off >>= 1) m = fmaxf(m, __shfl_xor(m, off));
  __shared__ float red[4], red2[4];
  const int w = t >> 6;
  if ((t & 63) == 0) red[w] = m;
  __syncthreads();
  m = fmaxf(fmaxf(red[0], red[1]), fmaxf(red[2], red[3]));
  float e[8], s = 0.f;
#pragma unroll
  for (int j = 0; j < 8; j++) { e[j] = __expf(f[j] - m); s += e[j]; }
#pragma unroll
  for (int off = 32; off > 0; off >>= 1) s += __shfl_xor(s, off);
  if ((t & 63) == 0) red2[w] = s;
  __syncthreads();
  s = red2[0] + red2[1] + red2[2] + red2[3];
  const float inv = 1.f / s;
  u16x8 o;
#pragma unroll
  for (int j = 0; j < 8; j++) o[j] = f2bf(e[j] * inv);
  *(u16x8*)(R + t * 8) = o;
}

extern "C" void kernel_launch(void* const* d_in, const int* in_sizes, int n_in,
                              void* d_out, int out_size, void* d_ws, size_t ws_size,
                              hipStream_t stream)
{
  const float* mf   = (const float*)d_in[0];   // [64,128,512]
  const float* x    = (const float*)d_in[1];   // [64,2048,512]
  const int*   mask = (const int*)d_in[2];     // [64,2048]
  const float* Wq   = (const float*)d_in[3];
  const float* Wk   = (const float*)d_in[4];
  const float* Wv   = (const float*)d_in[5];
  float* out = (float*)d_out;

  u16* ws  = (u16*)d_ws;
  u16* Wb  = ws;                     // 1536*512 = 786432 u16
  u16* mfb = Wb + 786432;            // 8192*512 = 4194304 u16
  u16* Qb  = mfb + 4194304;          // 8192*512 = 4194304 u16
  u16* dyn = Qb + 4194304;

  // per-batch: xb(2MB) + K(2MB) + Vt(2MB) + S(0.5MB) = 6815744 B
  const size_t fixedB = (size_t)(786432 + 4194304 + 4194304) * 2;
  int CB = 64;
  while (CB > 1 && fixedB + (size_t)CB * 6815744ull > ws_size) CB >>= 1;

  u16* xbc = dyn;                               // [CB*2048, 512] bf16
  u16* Kc  = xbc + (size_t)CB * 1048576;        // [CB*2048, 512]
  u16* Vtc = Kc  + (size_t)CB * 1048576;        // [CB, 512, 2048]
  u16* Sc  = Vtc + (size_t)CB * 1048576;        // [CB, 128, 2048]

  const float scale = 0.044194173824159216f;    // 1/sqrt(512)

  wconv_k<<<768, 256, 0, stream>>>(Wq, Wk, Wv, Wb);
  cvt_k<<<2048, 256, 0, stream>>>(mf, mfb);

  // Q projection: M=8192, N=512, K=512
  gemm_k<0><<<dim3(4, 64, 1), 256, 0, stream>>>(
      mfb, Wb, Qb, nullptr, 512, 0, 0, 0, 0, 512, 1.f);

  for (int bc = 0; bc < 64; bc += CB) {
    const float* xc = x + (long)bc * 2048 * 512;
    cvt_k<<<CB * 512, 256, 0, stream>>>(xc, xbc);
    // fused K+V projection, 8-phase 256x256 kernel
    kv8_k<<<dim3(4, CB * 8, 1), 512, 0, stream>>>(xbc, Wb + 262144, Kc, Vtc);
    // scores: S[q,kv] = (Q K^T)*scale - (1-mask)*1e10  (bf16)
    gemm_k<2><<<dim3(16, 1, CB), 256, 0, stream>>>(
        Qb + (long)bc * 65536, Kc, Sc, mask + (long)bc * 2048,
        512, 65536, 1048576, 262144, 2048, 2048, scale);
    softmax_k<<<CB * 128, 256, 0, stream>>>(Sc);
    // PV: out = relu(P V^T), K=2048, f32 out
    gemm_k<3><<<dim3(4, 1, CB), 256, 0, stream>>>(
        Sc, Vtc, out + (long)bc * 65536, nullptr,
        2048, 262144, 1048576, 65536, 0, 512, 1.f);
  }
}